// Round 10
// baseline (150.977 us; speedup 1.0000x reference)
//
#include <hip/hip_runtime.h>
#include <hip/hip_bf16.h>
#include <math.h>

// B,T,E,WIN,OC,VOCAB = 256,2048,128,5,128,50000
#define B_   256
#define T_   2048
#define E_   128
#define WIN_ 5
#define PAD_ 2
#define OC_  128
#define VOCAB_MAX 50000
#define VOCAB1 50001
#define TT   64
#define REAL_ROWS (TT + WIN_ - 1)
#define ROWS 80
#define ASTR 136                  // LDS row stride (bf16): 272B -> 2-way alias = free
#define VROWS 64                  // vocab rows per build_tables block

typedef __attribute__((ext_vector_type(8))) short short8;
typedef __attribute__((ext_vector_type(4))) float floatx4;
typedef __attribute__((ext_vector_type(4))) unsigned uintx4;

static __device__ __forceinline__ short f2bf(float f) {
    union { __hip_bfloat16 h; short s; } u;
    u.h = __float2bfloat16(f);
    return u.s;
}

__device__ __forceinline__ void atomicMaxFloat(float* addr, float v) {
    // requires init to -inf: works on both sign paths
    if (v >= 0.0f) atomicMax((int*)addr, __float_as_int(v));
    else           atomicMin((unsigned int*)addr, __float_as_uint(v));
}

// ============ P1: vocab-level tables ============
// D[v][o] = <emb[v], cnn_w[o]>  (bf16)
// r[v][k] = <emb[v], att_w[k]>  (fp32, k<5; slots 5..7 zero)
// Also initializes out[] to -inf (blocks 0..127).
__launch_bounds__(256, 4)
__global__ void build_tables(const float* __restrict__ emb,
                             const float* __restrict__ cnn_w,
                             const float* __restrict__ att_w,
                             short* __restrict__ D,
                             float* __restrict__ r,
                             float* __restrict__ out) {
    __shared__ short sh_a[VROWS * ASTR];   // 17408 B

    const int tid  = threadIdx.x;
    const int lane = tid & 63;
    const int w    = tid >> 6;
    const int l15  = lane & 15;
    const int quad = lane >> 4;
    const int v0   = blockIdx.x * VROWS;

    if (blockIdx.x < (B_ * OC_) / 256)
        out[blockIdx.x * 256 + tid] = -INFINITY;

    // stage 64 vocab rows fp32 -> bf16 (coalesced; clamp OOB rows)
    #pragma unroll
    for (int t = 0; t < 8; t++) {
        int i   = t * 256 + tid;
        int row = i >> 5, c4 = i & 31;
        int vr  = v0 + row; if (vr > VOCAB_MAX) vr = VOCAB_MAX;
        float4 v = *(const float4*)(emb + (size_t)vr * E_ + c4 * 4);
        short4 o; o.x = f2bf(v.x); o.y = f2bf(v.y); o.z = f2bf(v.z); o.w = f2bf(v.w);
        *(short4*)(&sh_a[row * ASTR + c4 * 4]) = o;
    }

    // B fragments (cnn_w fp32 -> bf16): wave w -> cols [w*32, w*32+32)
    short8 Bf[2][4];
    #pragma unroll
    for (int j = 0; j < 2; j++)
        #pragma unroll
        for (int ks = 0; ks < 4; ks++) {
            const float4* p = (const float4*)(cnn_w + (size_t)(w * 32 + j * 16 + l15) * E_ + ks * 32 + quad * 8);
            float4 p0 = p[0], p1 = p[1];
            Bf[j][ks] = (short8){ f2bf(p0.x), f2bf(p0.y), f2bf(p0.z), f2bf(p0.w),
                                  f2bf(p1.x), f2bf(p1.y), f2bf(p1.z), f2bf(p1.w) };
        }

    // att-tap fragments (taps >= WIN_ are zero)
    short8 Ba[4];
    #pragma unroll
    for (int ks = 0; ks < 4; ks++) {
        short8 v = (short8){0,0,0,0,0,0,0,0};
        if (l15 < WIN_) {
            const float4* p = (const float4*)(att_w + (size_t)l15 * E_ + ks * 32 + quad * 8);
            float4 p0 = p[0], p1 = p[1];
            v = (short8){ f2bf(p0.x), f2bf(p0.y), f2bf(p0.z), f2bf(p0.w),
                          f2bf(p1.x), f2bf(p1.y), f2bf(p1.z), f2bf(p1.w) };
        }
        Ba[ks] = v;
    }
    __syncthreads();

    // D tiles: 4 m-tiles x 2 n-tiles per wave
    #pragma unroll
    for (int mt = 0; mt < 4; mt++) {
        short8 a[4];
        #pragma unroll
        for (int ks = 0; ks < 4; ks++)
            a[ks] = *(const short8*)(&sh_a[(mt * 16 + l15) * ASTR + ks * 32 + quad * 8]);
        #pragma unroll
        for (int j = 0; j < 2; j++) {
            floatx4 acc = (floatx4){0.f, 0.f, 0.f, 0.f};
            #pragma unroll
            for (int ks = 0; ks < 4; ks++)
                acc = __builtin_amdgcn_mfma_f32_16x16x32_bf16(a[ks], Bf[j][ks], acc, 0, 0, 0);
            #pragma unroll
            for (int rr = 0; rr < 4; rr++) {
                int v = v0 + mt * 16 + quad * 4 + rr;
                if (v <= VOCAB_MAX)
                    D[(size_t)v * E_ + w * 32 + j * 16 + l15] = f2bf(acc[rr]);
            }
        }
    }

    // r tile: wave w handles m-tile w
    {
        short8 a[4];
        #pragma unroll
        for (int ks = 0; ks < 4; ks++)
            a[ks] = *(const short8*)(&sh_a[(w * 16 + l15) * ASTR + ks * 32 + quad * 8]);
        floatx4 acc = (floatx4){0.f, 0.f, 0.f, 0.f};
        #pragma unroll
        for (int ks = 0; ks < 4; ks++)
            acc = __builtin_amdgcn_mfma_f32_16x16x32_bf16(a[ks], Ba[ks], acc, 0, 0, 0);
        if (l15 < 8) {
            #pragma unroll
            for (int rr = 0; rr < 4; rr++) {
                int v = v0 + w * 16 + quad * 4 + rr;
                if (v <= VOCAB_MAX) r[(size_t)v * 8 + l15] = acc[rr];
            }
        }
    }
}

// ============ P2: streaming score + max, L2-partitioned by col-chunk ============
// blockIdx.x = tchunk*4 + cc; cc = col-chunk of 32 cols (3.2 MB D-slice -> fits
// one XCD's 4 MB L2; round-robin block->XCD maps XCD k to chunk k%4).
// Wave: 64 tokens; lane: lt = token-in-16-group (lane>>2), lq = 8-col sub (lane&3).
__launch_bounds__(256, 8)
__global__ void score_max(const int* __restrict__ x,
                          const short* __restrict__ D,
                          const float* __restrict__ r,
                          const float* __restrict__ att_b_p,
                          const float* __restrict__ cnn_b,
                          float* __restrict__ out) {
    __shared__ int   sh_x[260];
    __shared__ float sh_sc[256];
    __shared__ float sh_red[4][32];

    const int tid  = threadIdx.x;
    const int lane = tid & 63;
    const int w    = tid >> 6;
    const int b    = blockIdx.y;
    const int cc   = blockIdx.x & 3;            // col chunk: cols [cc*32, cc*32+32)
    const int t0   = (blockIdx.x >> 2) * 256;
    const int lq   = lane & 3;                  // 8-col sub-chunk within the 32
    const int lt   = lane >> 2;                 // token within 16-group

    for (int i = tid; i < 260; i += 256) {
        int t = t0 + i - PAD_;
        sh_x[i] = (t >= 0 && t < T_) ? x[b * T_ + t] : -1;
    }
    __syncthreads();

    // scores: one token per thread (recomputed per col-chunk; r is tiny/L2-hot)
    {
        float s = att_b_p[0];
        #pragma unroll
        for (int k = 0; k < WIN_; k++) {
            int v = sh_x[tid + k];
            if (v >= 0) s += r[(size_t)v * 8 + k];
        }
        sh_sc[tid] = 1.0f / (1.0f + __expf(-s));
    }
    __syncthreads();

    // max over this wave's 64 tokens for 8 cols/lane; 4 independent loads batched
    float mm[8];
    #pragma unroll
    for (int c = 0; c < 8; c++) mm[c] = -INFINITY;

    const int base_t = w * 64;
    uintx4 u[4];
    float  sc4[4];
    #pragma unroll
    for (int g = 0; g < 4; g++) {
        int tok = base_t + g * 16 + lt;
        int v   = sh_x[tok + PAD_];             // always a valid token here
        sc4[g]  = sh_sc[tok];
        u[g]    = *(const uintx4*)(D + (size_t)v * E_ + cc * 32 + lq * 8);
    }
    #pragma unroll
    for (int g = 0; g < 4; g++) {
        #pragma unroll
        for (int q = 0; q < 4; q++) {
            float lo = __uint_as_float(u[g][q] << 16);
            float hi = __uint_as_float(u[g][q] & 0xFFFF0000u);
            mm[q * 2]     = fmaxf(mm[q * 2],     sc4[g] * lo);
            mm[q * 2 + 1] = fmaxf(mm[q * 2 + 1], sc4[g] * hi);
        }
    }
    // reduce across lanes sharing lq (stride 4): xor 4,8,16,32
    #pragma unroll
    for (int c = 0; c < 8; c++) {
        mm[c] = fmaxf(mm[c], __shfl_xor(mm[c], 4));
        mm[c] = fmaxf(mm[c], __shfl_xor(mm[c], 8));
        mm[c] = fmaxf(mm[c], __shfl_xor(mm[c], 16));
        mm[c] = fmaxf(mm[c], __shfl_xor(mm[c], 32));
    }
    if (lane < 4) {
        #pragma unroll
        for (int c = 0; c < 8; c++) sh_red[w][lane * 8 + c] = mm[c];
    }
    __syncthreads();
    if (tid < 32) {
        float m = fmaxf(fmaxf(sh_red[0][tid], sh_red[1][tid]),
                        fmaxf(sh_red[2][tid], sh_red[3][tid]));
        int o = cc * 32 + tid;
        atomicMaxFloat(&out[b * OC_ + o], tanhf(m + cnn_b[o]));
    }
}

// ============ fallback (small ws): monolithic fp32-gather version ============
__global__ void prep_small(const float* __restrict__ cnn_w, const float* __restrict__ att_w,
                           short* __restrict__ wsw, short* __restrict__ wsatt) {
    int i = blockIdx.x * 256 + threadIdx.x;
    if (i < OC_ * E_)  wsw[i]   = f2bf(cnn_w[i]);
    if (i < WIN_ * E_) wsatt[i] = f2bf(att_w[i]);
}

__launch_bounds__(256, 4)
__global__ void fallback_main(const int* __restrict__ x,
                              const float* __restrict__ emb,
                              const float* __restrict__ att_b_p,
                              const short* __restrict__ wsw,
                              const short* __restrict__ wsatt,
                              const float* __restrict__ cnn_b,
                              float* __restrict__ out) {
    __shared__ short sh_a[ROWS * ASTR];
    __shared__ short sh_att[16 * ASTR];
    __shared__ float sh_r[ROWS * 8];
    __shared__ float sh_score[TT];
    __shared__ int   sh_idx[8 * ROWS];

    const int tid  = threadIdx.x;
    const int lane = tid & 63;
    const int w    = tid >> 6;
    const int b    = blockIdx.y;
    const int t0   = blockIdx.x * (8 * TT);
    const int l15  = lane & 15;
    const int quad = lane >> 4;
    const int rbase = tid >> 4;
    const int c     = tid & 15;

    for (int i = tid; i < 8 * ROWS; i += 256) {
        int tile = i / ROWS, row = i - tile * ROWS;
        int t = t0 + tile * TT + row - PAD_;
        sh_idx[i] = (row < REAL_ROWS && t >= 0 && t < T_) ? x[b * T_ + t] : -1;
    }
    {
        int o = tid >> 4, cc = tid & 15;
        short8 v = (short8){0,0,0,0,0,0,0,0};
        if (o < WIN_) v = *(const short8*)(wsatt + o * E_ + cc * 8);
        *(short8*)(&sh_att[o * ASTR + cc * 8]) = v;
    }
    short8 Bf[2][4];
    #pragma unroll
    for (int j = 0; j < 2; j++)
        #pragma unroll
        for (int ks = 0; ks < 4; ks++)
            Bf[j][ks] = *(const short8*)(wsw + (size_t)(w * 32 + j * 16 + l15) * E_ + ks * 32 + quad * 8);
    __syncthreads();

    short8 g[5];
    #pragma unroll
    for (int k = 0; k < 5; k++) {
        int idx = sh_idx[rbase + 16 * k];
        short8 v = (short8){0,0,0,0,0,0,0,0};
        if (idx >= 0) {
            const float4* p = (const float4*)(emb + (size_t)idx * E_ + c * 8);
            float4 p0 = p[0], p1 = p[1];
            v = (short8){ f2bf(p0.x), f2bf(p0.y), f2bf(p0.z), f2bf(p0.w),
                          f2bf(p1.x), f2bf(p1.y), f2bf(p1.z), f2bf(p1.w) };
        }
        g[k] = v;
    }
    #pragma unroll
    for (int k = 0; k < 5; k++)
        *(short8*)(&sh_a[(rbase + 16 * k) * ASTR + c * 8]) = g[k];
    __syncthreads();

    const float attb = att_b_p[0];
    float mm[2] = { -INFINITY, -INFINITY };

    for (int it = 0; it < 8; it++) {
        for (int mt = w; mt < 5; mt += 4) {
            floatx4 acc = (floatx4){0.f, 0.f, 0.f, 0.f};
            #pragma unroll
            for (int ks = 0; ks < 4; ks++) {
                short8 a  = *(const short8*)(&sh_a[(mt * 16 + l15) * ASTR + ks * 32 + quad * 8]);
                short8 bs = *(const short8*)(&sh_att[l15 * ASTR + ks * 32 + quad * 8]);
                acc = __builtin_amdgcn_mfma_f32_16x16x32_bf16(a, bs, acc, 0, 0, 0);
            }
            if (l15 < 8) {
                #pragma unroll
                for (int r = 0; r < 4; r++)
                    sh_r[(mt * 16 + quad * 4 + r) * 8 + l15] = acc[r];
            }
        }
        __syncthreads();

        if (it + 1 < 8) {
            const int* idxp = &sh_idx[(it + 1) * ROWS];
            #pragma unroll
            for (int k = 0; k < 5; k++) {
                int idx = idxp[rbase + 16 * k];
                short8 v = (short8){0,0,0,0,0,0,0,0};
                if (idx >= 0) {
                    const float4* p = (const float4*)(emb + (size_t)idx * E_ + c * 8);
                    float4 p0 = p[0], p1 = p[1];
                    v = (short8){ f2bf(p0.x), f2bf(p0.y), f2bf(p0.z), f2bf(p0.w),
                                  f2bf(p1.x), f2bf(p1.y), f2bf(p1.z), f2bf(p1.w) };
                }
                g[k] = v;
            }
        }

        if (tid < TT) {
            float s = attb;
            #pragma unroll
            for (int k = 0; k < WIN_; k++) s += sh_r[(tid + k) * 8 + k];
            sh_score[tid] = 1.0f / (1.0f + __expf(-s));
        }

        floatx4 acc[4][2];
        #pragma unroll
        for (int i = 0; i < 4; i++)
            #pragma unroll
            for (int j = 0; j < 2; j++) acc[i][j] = (floatx4){0.f, 0.f, 0.f, 0.f};
        #pragma unroll
        for (int ks = 0; ks < 4; ks++) {
            int ko = ks * 32 + quad * 8;
            #pragma unroll
            for (int i = 0; i < 4; i++) {
                short8 ai = *(const short8*)(&sh_a[(PAD_ + i * 16 + l15) * ASTR + ko]);
                acc[i][0] = __builtin_amdgcn_mfma_f32_16x16x32_bf16(ai, Bf[0][ks], acc[i][0], 0, 0, 0);
                acc[i][1] = __builtin_amdgcn_mfma_f32_16x16x32_bf16(ai, Bf[1][ks], acc[i][1], 0, 0, 0);
            }
        }
        __syncthreads();

        #pragma unroll
        for (int i = 0; i < 4; i++) {
            #pragma unroll
            for (int r = 0; r < 4; r++) {
                float sc = sh_score[i * 16 + quad * 4 + r];
                mm[0] = fmaxf(mm[0], sc * acc[i][0][r]);
                mm[1] = fmaxf(mm[1], sc * acc[i][1][r]);
            }
        }

        if (it + 1 < 8) {
            #pragma unroll
            for (int k = 0; k < 5; k++)
                *(short8*)(&sh_a[(rbase + 16 * k) * ASTR + c * 8]) = g[k];
            __syncthreads();
        }
    }

    #pragma unroll
    for (int j = 0; j < 2; j++) {
        float m = mm[j];
        m = fmaxf(m, __shfl_xor(m, 16));
        m = fmaxf(m, __shfl_xor(m, 32));
        if (lane < 16) {
            int o = w * 32 + j * 16 + lane;
            atomicMaxFloat(&out[b * OC_ + o], tanhf(m + cnn_b[o]));
        }
    }
}

extern "C" void kernel_launch(void* const* d_in, const int* in_sizes, int n_in,
                              void* d_out, int out_size, void* d_ws, size_t ws_size,
                              hipStream_t stream) {
    const int*   x     = (const int*)d_in[0];
    const float* emb   = (const float*)d_in[1];
    const float* att_w = (const float*)d_in[2];
    const float* att_b = (const float*)d_in[3];
    const float* cnn_w = (const float*)d_in[4];
    const float* cnn_b = (const float*)d_in[5];
    float* out = (float*)d_out;

    const size_t d_elems = (size_t)VOCAB1 * E_;     // bf16 count
    const size_t r_elems = (size_t)VOCAB1 * 8;      // fp32 count
    const size_t need = d_elems * 2 + r_elems * 4 + 64;

    if (ws_size >= need) {
        short* Dt = (short*)d_ws;
        float* rt = (float*)(Dt + d_elems);
        build_tables<<<(VOCAB1 + VROWS - 1) / VROWS, 256, 0, stream>>>(emb, cnn_w, att_w, Dt, rt, out);
        dim3 grid((T_ / 256) * 4, B_);               // (32, 256) = 8192 blocks
        score_max<<<grid, 256, 0, stream>>>(x, Dt, rt, att_b, cnn_b, out);
    } else {
        hipMemsetAsync(d_out, 0xFF, (size_t)B_ * OC_ * sizeof(float), stream);
        short* ws_w   = (short*)d_ws;
        short* ws_att = ws_w + OC_ * E_;
        prep_small<<<16, 256, 0, stream>>>(cnn_w, att_w, ws_w, ws_att);
        dim3 grid(T_ / (8 * TT), B_);
        fallback_main<<<grid, 256, 0, stream>>>(x, emb, att_b, ws_w, ws_att, cnn_b, out);
    }
}

// Round 11
// 111.734 us; speedup vs baseline: 1.3512x; 1.3512x over previous
//
#include <hip/hip_runtime.h>
#include <hip/hip_bf16.h>
#include <math.h>

// B,T,E,WIN,OC,VOCAB = 256,2048,128,5,128,50000
#define B_   256
#define T_   2048
#define E_   128
#define WIN_ 5
#define PAD_ 2
#define OC_  128
#define VOCAB_MAX 50000
#define VOCAB1 50001
#define TT   64
#define REAL_ROWS (TT + WIN_ - 1)
#define ROWS 80
#define ASTR 136                  // LDS row stride (bf16): 272B -> 2-way alias = free
#define VROWS 64                  // vocab rows per build_tables block
#define BT   512                  // tokens per score_max block

typedef __attribute__((ext_vector_type(8))) short short8;
typedef __attribute__((ext_vector_type(4))) float floatx4;
typedef __attribute__((ext_vector_type(4))) unsigned uintx4;

static __device__ __forceinline__ short f2bf(float f) {
    union { __hip_bfloat16 h; short s; } u;
    u.h = __float2bfloat16(f);
    return u.s;
}

__device__ __forceinline__ void atomicMaxFloat(float* addr, float v) {
    // requires init to -inf: works on both sign paths
    if (v >= 0.0f) atomicMax((int*)addr, __float_as_int(v));
    else           atomicMin((unsigned int*)addr, __float_as_uint(v));
}

// ============ P1: vocab-level tables ============
// D[v][o] = <emb[v], cnn_w[o]>  (bf16)
// r[v][k] = <emb[v], att_w[k]>  (fp32, k<5; slots 5..7 zero)
// Also initializes out[] to -inf (blocks 0..127).
__launch_bounds__(256, 4)
__global__ void build_tables(const float* __restrict__ emb,
                             const float* __restrict__ cnn_w,
                             const float* __restrict__ att_w,
                             short* __restrict__ D,
                             float* __restrict__ r,
                             float* __restrict__ out) {
    __shared__ short sh_a[VROWS * ASTR];   // 17408 B

    const int tid  = threadIdx.x;
    const int lane = tid & 63;
    const int w    = tid >> 6;
    const int l15  = lane & 15;
    const int quad = lane >> 4;
    const int v0   = blockIdx.x * VROWS;

    if (blockIdx.x < (B_ * OC_) / 256)
        out[blockIdx.x * 256 + tid] = -INFINITY;

    // stage 64 vocab rows fp32 -> bf16 (coalesced; clamp OOB rows)
    #pragma unroll
    for (int t = 0; t < 8; t++) {
        int i   = t * 256 + tid;
        int row = i >> 5, c4 = i & 31;
        int vr  = v0 + row; if (vr > VOCAB_MAX) vr = VOCAB_MAX;
        float4 v = *(const float4*)(emb + (size_t)vr * E_ + c4 * 4);
        short4 o; o.x = f2bf(v.x); o.y = f2bf(v.y); o.z = f2bf(v.z); o.w = f2bf(v.w);
        *(short4*)(&sh_a[row * ASTR + c4 * 4]) = o;
    }

    // B fragments (cnn_w fp32 -> bf16): wave w -> cols [w*32, w*32+32)
    short8 Bf[2][4];
    #pragma unroll
    for (int j = 0; j < 2; j++)
        #pragma unroll
        for (int ks = 0; ks < 4; ks++) {
            const float4* p = (const float4*)(cnn_w + (size_t)(w * 32 + j * 16 + l15) * E_ + ks * 32 + quad * 8);
            float4 p0 = p[0], p1 = p[1];
            Bf[j][ks] = (short8){ f2bf(p0.x), f2bf(p0.y), f2bf(p0.z), f2bf(p0.w),
                                  f2bf(p1.x), f2bf(p1.y), f2bf(p1.z), f2bf(p1.w) };
        }

    // att-tap fragments (taps >= WIN_ are zero)
    short8 Ba[4];
    #pragma unroll
    for (int ks = 0; ks < 4; ks++) {
        short8 v = (short8){0,0,0,0,0,0,0,0};
        if (l15 < WIN_) {
            const float4* p = (const float4*)(att_w + (size_t)l15 * E_ + ks * 32 + quad * 8);
            float4 p0 = p[0], p1 = p[1];
            v = (short8){ f2bf(p0.x), f2bf(p0.y), f2bf(p0.z), f2bf(p0.w),
                          f2bf(p1.x), f2bf(p1.y), f2bf(p1.z), f2bf(p1.w) };
        }
        Ba[ks] = v;
    }
    __syncthreads();

    // D tiles: 4 m-tiles x 2 n-tiles per wave
    #pragma unroll
    for (int mt = 0; mt < 4; mt++) {
        short8 a[4];
        #pragma unroll
        for (int ks = 0; ks < 4; ks++)
            a[ks] = *(const short8*)(&sh_a[(mt * 16 + l15) * ASTR + ks * 32 + quad * 8]);
        #pragma unroll
        for (int j = 0; j < 2; j++) {
            floatx4 acc = (floatx4){0.f, 0.f, 0.f, 0.f};
            #pragma unroll
            for (int ks = 0; ks < 4; ks++)
                acc = __builtin_amdgcn_mfma_f32_16x16x32_bf16(a[ks], Bf[j][ks], acc, 0, 0, 0);
            #pragma unroll
            for (int rr = 0; rr < 4; rr++) {
                int v = v0 + mt * 16 + quad * 4 + rr;
                if (v <= VOCAB_MAX)
                    D[(size_t)v * E_ + w * 32 + j * 16 + l15] = f2bf(acc[rr]);
            }
        }
    }

    // r tile: wave w handles m-tile w
    {
        short8 a[4];
        #pragma unroll
        for (int ks = 0; ks < 4; ks++)
            a[ks] = *(const short8*)(&sh_a[(w * 16 + l15) * ASTR + ks * 32 + quad * 8]);
        floatx4 acc = (floatx4){0.f, 0.f, 0.f, 0.f};
        #pragma unroll
        for (int ks = 0; ks < 4; ks++)
            acc = __builtin_amdgcn_mfma_f32_16x16x32_bf16(a[ks], Ba[ks], acc, 0, 0, 0);
        if (l15 < 8) {
            #pragma unroll
            for (int rr = 0; rr < 4; rr++) {
                int v = v0 + w * 16 + quad * 4 + rr;
                if (v <= VOCAB_MAX) r[(size_t)v * 8 + l15] = acc[rr];
            }
        }
    }
}

// ============ P2: streaming score + max (512 tokens/block) ============
// Scores via r-row LDS trick: score[t] = sum_k rt[k][t+k], one 20B gather/token.
// Max phase: wave = 128 tokens, 8 independent dwordx4 D-gathers in flight.
__launch_bounds__(256, 6)
__global__ void score_max(const int* __restrict__ x,
                          const short* __restrict__ D,
                          const float* __restrict__ r,
                          const float* __restrict__ att_b_p,
                          const float* __restrict__ cnn_b,
                          float* __restrict__ out) {
    __shared__ int   sh_x[BT + 4];          // 2064 B
    __shared__ float sh_rt[WIN_][BT + 8];   // 10400 B (SoA: conflict-free)
    __shared__ float sh_sc[BT];             // 2048 B
    __shared__ float sh_red[4][128];        // 2048 B  -> ~16.6 KB

    const int tid  = threadIdx.x;
    const int lane = tid & 63;
    const int w    = tid >> 6;
    const int b    = blockIdx.y;
    const int t0   = blockIdx.x * BT;
    const int l15  = lane & 15;
    const int grp  = lane >> 4;

    // phase 1: token indices (tokens t0-2 .. t0+BT+1)
    for (int i = tid; i < BT + 4; i += 256) {
        int t = t0 + i - PAD_;
        sh_x[i] = (t >= 0 && t < T_) ? x[b * T_ + t] : -1;
    }
    __syncthreads();

    // phase 2: gather each token's r-row (taps 0..4) into SoA LDS
    for (int i = tid; i < BT + 4; i += 256) {
        int v = sh_x[i];
        float4 r03 = make_float4(0.f, 0.f, 0.f, 0.f);
        float  r4  = 0.f;
        if (v >= 0) {
            r03 = *(const float4*)(r + (size_t)v * 8);
            r4  = r[(size_t)v * 8 + 4];
        }
        sh_rt[0][i] = r03.x; sh_rt[1][i] = r03.y; sh_rt[2][i] = r03.z;
        sh_rt[3][i] = r03.w; sh_rt[4][i] = r4;
    }
    __syncthreads();

    // phase 3: window-sum + sigmoid (LDS only)
    {
        const float attb = att_b_p[0];
        #pragma unroll
        for (int rep = 0; rep < 2; rep++) {
            int j = rep * 256 + tid;
            float s = attb;
            #pragma unroll
            for (int k = 0; k < WIN_; k++) s += sh_rt[k][j + k];
            sh_sc[j] = 1.0f / (1.0f + __expf(-s));
        }
    }
    __syncthreads();

    // phase 4: max over wave's 128 tokens; lane owns cols [l15*8, l15*8+8)
    float mm[8];
    #pragma unroll
    for (int c = 0; c < 8; c++) mm[c] = -INFINITY;

    const int base_t = w * 128;
    for (int batch = 0; batch < 4; batch++) {
        uintx4 u[8];
        float  sc8[8];
        const int start = base_t + batch * 32;
        #pragma unroll
        for (int j = 0; j < 8; j++) {
            int tok = start + j * 4 + grp;
            int v   = sh_x[tok + PAD_];          // always a valid token here
            sc8[j]  = sh_sc[tok];
            u[j]    = *(const uintx4*)(D + (size_t)v * E_ + l15 * 8);
        }
        #pragma unroll
        for (int j = 0; j < 8; j++) {
            #pragma unroll
            for (int q = 0; q < 4; q++) {
                float lo = __uint_as_float(u[j][q] << 16);
                float hi = __uint_as_float(u[j][q] & 0xFFFF0000u);
                mm[q * 2]     = fmaxf(mm[q * 2],     sc8[j] * lo);
                mm[q * 2 + 1] = fmaxf(mm[q * 2 + 1], sc8[j] * hi);
            }
        }
    }
    // fold across the 4 token-groups (lanes sharing l15)
    #pragma unroll
    for (int c = 0; c < 8; c++) {
        mm[c] = fmaxf(mm[c], __shfl_xor(mm[c], 16));
        mm[c] = fmaxf(mm[c], __shfl_xor(mm[c], 32));
    }
    if (lane < 16) {
        #pragma unroll
        for (int c = 0; c < 8; c++) sh_red[w][l15 * 8 + c] = mm[c];
    }
    __syncthreads();
    if (tid < 128) {
        float m = fmaxf(fmaxf(sh_red[0][tid], sh_red[1][tid]),
                        fmaxf(sh_red[2][tid], sh_red[3][tid]));
        atomicMaxFloat(&out[b * OC_ + tid], tanhf(m + cnn_b[tid]));
    }
}

// ============ fallback (small ws): monolithic fp32-gather version ============
__global__ void prep_small(const float* __restrict__ cnn_w, const float* __restrict__ att_w,
                           short* __restrict__ wsw, short* __restrict__ wsatt) {
    int i = blockIdx.x * 256 + threadIdx.x;
    if (i < OC_ * E_)  wsw[i]   = f2bf(cnn_w[i]);
    if (i < WIN_ * E_) wsatt[i] = f2bf(att_w[i]);
}

__launch_bounds__(256, 4)
__global__ void fallback_main(const int* __restrict__ x,
                              const float* __restrict__ emb,
                              const float* __restrict__ att_b_p,
                              const short* __restrict__ wsw,
                              const short* __restrict__ wsatt,
                              const float* __restrict__ cnn_b,
                              float* __restrict__ out) {
    __shared__ short sh_a[ROWS * ASTR];
    __shared__ short sh_att[16 * ASTR];
    __shared__ float sh_r[ROWS * 8];
    __shared__ float sh_score[TT];
    __shared__ int   sh_idx[8 * ROWS];

    const int tid  = threadIdx.x;
    const int lane = tid & 63;
    const int w    = tid >> 6;
    const int b    = blockIdx.y;
    const int t0   = blockIdx.x * (8 * TT);
    const int l15  = lane & 15;
    const int quad = lane >> 4;
    const int rbase = tid >> 4;
    const int c     = tid & 15;

    for (int i = tid; i < 8 * ROWS; i += 256) {
        int tile = i / ROWS, row = i - tile * ROWS;
        int t = t0 + tile * TT + row - PAD_;
        sh_idx[i] = (row < REAL_ROWS && t >= 0 && t < T_) ? x[b * T_ + t] : -1;
    }
    {
        int o = tid >> 4, cc = tid & 15;
        short8 v = (short8){0,0,0,0,0,0,0,0};
        if (o < WIN_) v = *(const short8*)(wsatt + o * E_ + cc * 8);
        *(short8*)(&sh_att[o * ASTR + cc * 8]) = v;
    }
    short8 Bf[2][4];
    #pragma unroll
    for (int j = 0; j < 2; j++)
        #pragma unroll
        for (int ks = 0; ks < 4; ks++)
            Bf[j][ks] = *(const short8*)(wsw + (size_t)(w * 32 + j * 16 + l15) * E_ + ks * 32 + quad * 8);
    __syncthreads();

    short8 g[5];
    #pragma unroll
    for (int k = 0; k < 5; k++) {
        int idx = sh_idx[rbase + 16 * k];
        short8 v = (short8){0,0,0,0,0,0,0,0};
        if (idx >= 0) {
            const float4* p = (const float4*)(emb + (size_t)idx * E_ + c * 8);
            float4 p0 = p[0], p1 = p[1];
            v = (short8){ f2bf(p0.x), f2bf(p0.y), f2bf(p0.z), f2bf(p0.w),
                          f2bf(p1.x), f2bf(p1.y), f2bf(p1.z), f2bf(p1.w) };
        }
        g[k] = v;
    }
    #pragma unroll
    for (int k = 0; k < 5; k++)
        *(short8*)(&sh_a[(rbase + 16 * k) * ASTR + c * 8]) = g[k];
    __syncthreads();

    const float attb = att_b_p[0];
    float mm[2] = { -INFINITY, -INFINITY };

    for (int it = 0; it < 8; it++) {
        for (int mt = w; mt < 5; mt += 4) {
            floatx4 acc = (floatx4){0.f, 0.f, 0.f, 0.f};
            #pragma unroll
            for (int ks = 0; ks < 4; ks++) {
                short8 a  = *(const short8*)(&sh_a[(mt * 16 + l15) * ASTR + ks * 32 + quad * 8]);
                short8 bs = *(const short8*)(&sh_att[l15 * ASTR + ks * 32 + quad * 8]);
                acc = __builtin_amdgcn_mfma_f32_16x16x32_bf16(a, bs, acc, 0, 0, 0);
            }
            if (l15 < 8) {
                #pragma unroll
                for (int r = 0; r < 4; r++)
                    sh_r[(mt * 16 + quad * 4 + r) * 8 + l15] = acc[r];
            }
        }
        __syncthreads();

        if (it + 1 < 8) {
            const int* idxp = &sh_idx[(it + 1) * ROWS];
            #pragma unroll
            for (int k = 0; k < 5; k++) {
                int idx = idxp[rbase + 16 * k];
                short8 v = (short8){0,0,0,0,0,0,0,0};
                if (idx >= 0) {
                    const float4* p = (const float4*)(emb + (size_t)idx * E_ + c * 8);
                    float4 p0 = p[0], p1 = p[1];
                    v = (short8){ f2bf(p0.x), f2bf(p0.y), f2bf(p0.z), f2bf(p0.w),
                                  f2bf(p1.x), f2bf(p1.y), f2bf(p1.z), f2bf(p1.w) };
                }
                g[k] = v;
            }
        }

        if (tid < TT) {
            float s = attb;
            #pragma unroll
            for (int k = 0; k < WIN_; k++) s += sh_r[(tid + k) * 8 + k];
            sh_score[tid] = 1.0f / (1.0f + __expf(-s));
        }

        floatx4 acc[4][2];
        #pragma unroll
        for (int i = 0; i < 4; i++)
            #pragma unroll
            for (int j = 0; j < 2; j++) acc[i][j] = (floatx4){0.f, 0.f, 0.f, 0.f};
        #pragma unroll
        for (int ks = 0; ks < 4; ks++) {
            int ko = ks * 32 + quad * 8;
            #pragma unroll
            for (int i = 0; i < 4; i++) {
                short8 ai = *(const short8*)(&sh_a[(PAD_ + i * 16 + l15) * ASTR + ko]);
                acc[i][0] = __builtin_amdgcn_mfma_f32_16x16x32_bf16(ai, Bf[0][ks], acc[i][0], 0, 0, 0);
                acc[i][1] = __builtin_amdgcn_mfma_f32_16x16x32_bf16(ai, Bf[1][ks], acc[i][1], 0, 0, 0);
            }
        }
        __syncthreads();

        #pragma unroll
        for (int i = 0; i < 4; i++) {
            #pragma unroll
            for (int r = 0; r < 4; r++) {
                float sc = sh_score[i * 16 + quad * 4 + r];
                mm[0] = fmaxf(mm[0], sc * acc[i][0][r]);
                mm[1] = fmaxf(mm[1], sc * acc[i][1][r]);
            }
        }

        if (it + 1 < 8) {
            #pragma unroll
            for (int k = 0; k < 5; k++)
                *(short8*)(&sh_a[(rbase + 16 * k) * ASTR + c * 8]) = g[k];
            __syncthreads();
        }
    }

    #pragma unroll
    for (int j = 0; j < 2; j++) {
        float m = mm[j];
        m = fmaxf(m, __shfl_xor(m, 16));
        m = fmaxf(m, __shfl_xor(m, 32));
        if (lane < 16) {
            int o = w * 32 + j * 16 + lane;
            atomicMaxFloat(&out[b * OC_ + o], tanhf(m + cnn_b[o]));
        }
    }
}

extern "C" void kernel_launch(void* const* d_in, const int* in_sizes, int n_in,
                              void* d_out, int out_size, void* d_ws, size_t ws_size,
                              hipStream_t stream) {
    const int*   x     = (const int*)d_in[0];
    const float* emb   = (const float*)d_in[1];
    const float* att_w = (const float*)d_in[2];
    const float* att_b = (const float*)d_in[3];
    const float* cnn_w = (const float*)d_in[4];
    const float* cnn_b = (const float*)d_in[5];
    float* out = (float*)d_out;

    const size_t d_elems = (size_t)VOCAB1 * E_;     // bf16 count
    const size_t r_elems = (size_t)VOCAB1 * 8;      // fp32 count
    const size_t need = d_elems * 2 + r_elems * 4 + 64;

    if (ws_size >= need) {
        short* Dt = (short*)d_ws;
        float* rt = (float*)(Dt + d_elems);
        build_tables<<<(VOCAB1 + VROWS - 1) / VROWS, 256, 0, stream>>>(emb, cnn_w, att_w, Dt, rt, out);
        dim3 grid(T_ / BT, B_);                      // (4, 256) = 1024 blocks
        score_max<<<grid, 256, 0, stream>>>(x, Dt, rt, att_b, cnn_b, out);
    } else {
        hipMemsetAsync(d_out, 0xFF, (size_t)B_ * OC_ * sizeof(float), stream);
        short* ws_w   = (short*)d_ws;
        short* ws_att = ws_w + OC_ * E_;
        prep_small<<<16, 256, 0, stream>>>(cnn_w, att_w, ws_w, ws_att);
        dim3 grid(T_ / (8 * TT), B_);
        fallback_main<<<grid, 256, 0, stream>>>(x, emb, att_b, ws_w, ws_att, cnn_b, out);
    }
}